// Round 1
// baseline (242.985 us; speedup 1.0000x reference)
//
#include <hip/hip_runtime.h>
#include <math.h>

#define NN   6464      // total nodes
#define NPER 101
#define HD   128
#define HE   16
#define NE   652864    // 64*101*101
#define PERB 10201     // 101*101
#define EPSB 1e-5f
#define SLOPE 0.2f

__global__ void k_zero(float* p, int n){
    int i = blockIdx.x*blockDim.x + threadIdx.x;
    if (i < n) p[i] = 0.f;
}

__global__ void k_reduce_eai(const float* __restrict__ eai, float* __restrict__ stats){
    __shared__ float ls[256], ls2[256];
    float s = 0.f, s2 = 0.f;
    for (int i = blockIdx.x*256 + threadIdx.x; i < NE; i += gridDim.x*256){
        float v = eai[i]; s += v; s2 += v*v;
    }
    int tid = threadIdx.x;
    ls[tid] = s; ls2[tid] = s2; __syncthreads();
    for (int o = 128; o > 0; o >>= 1){
        if (tid < o){ ls[tid] += ls[tid+o]; ls2[tid] += ls2[tid+o]; }
        __syncthreads();
    }
    if (tid == 0){ atomicAdd(&stats[0], ls[0]); atomicAdd(&stats[1], ls2[0]); }
}

// Build per-layer c1[h], d[h] from edge-attr batch stats:
//   ea_bn[e,k] = eai[e]*A[k] + B[k];  ea_bn @ We = eai*c1 + c2;  d = c2 + attn_b
__global__ void k_setup(const float* __restrict__ stats, const float* __restrict__ few,
                        const float* __restrict__ beg, const float* __restrict__ beb,
                        const float* __restrict__ attn_w, const float* __restrict__ attn_b,
                        float* __restrict__ c1, float* __restrict__ dv){
    __shared__ float sA[HE], sB[HE];
    int tid = threadIdx.x;                 // 128 threads = h
    float mean = stats[0] * (1.f/NE);
    float var  = stats[1] * (1.f/NE) - mean*mean;
    if (tid < HE){
        float w = few[tid];
        float a = w * rsqrtf(var*w*w + EPSB) * beg[tid];
        sA[tid] = a; sB[tid] = beb[tid] - mean*a;
    }
    __syncthreads();
    for (int l = 0; l < 3; l++){
        const float* W = attn_w + (l*272 + 256)*HD;   // We rows (256..271)
        float a1 = 0.f, a2 = 0.f;
        for (int k = 0; k < HE; k++){
            float wv = W[k*HD + tid];
            a1 += sA[k]*wv; a2 += sB[k]*wv;
        }
        c1[l*HD + tid] = a1;
        dv[l*HD + tid] = a2 + attn_b[l*HD + tid];
    }
}

// h0 = [x,demand] @ fc_node_w + b, then training-mode BatchNorm over all N rows.
// One block per channel k.
__global__ __launch_bounds__(256) void k_node_bn(const float* __restrict__ x, const float* __restrict__ demand,
                          const float* __restrict__ w, const float* __restrict__ b,
                          const float* __restrict__ g, const float* __restrict__ beta,
                          float* __restrict__ hbuf){
    int k = blockIdx.x, tid = threadIdx.x;
    float w0 = w[k], w1 = w[HD+k], w2 = w[2*HD+k], bb = b[k];
    float s = 0.f, s2 = 0.f;
    for (int n = tid; n < NN; n += 256){
        float p = x[2*n]*w0 + x[2*n+1]*w1 + demand[n]*w2 + bb;
        s += p; s2 += p*p;
    }
    __shared__ float ls[256], ls2[256];
    ls[tid] = s; ls2[tid] = s2; __syncthreads();
    for (int o = 128; o > 0; o >>= 1){
        if (tid < o){ ls[tid] += ls[tid+o]; ls2[tid] += ls2[tid+o]; }
        __syncthreads();
    }
    __shared__ float smu, srs;
    if (tid == 0){
        float mu = ls[0]*(1.f/NN);
        float var = ls2[0]*(1.f/NN) - mu*mu;
        smu = mu; srs = rsqrtf(var + EPSB);
    }
    __syncthreads();
    float mu = smu, rs = srs, gg = g[k], be = beta[k];
    for (int n = tid; n < NN; n += 256){
        float p = x[2*n]*w0 + x[2*n+1]*w1 + demand[n]*w2 + bb;
        hbuf[n*HD + k] = (p - mu)*rs*gg + be;
    }
}

// Fused per-node GEMMs: t = h@fc_w[l]+fc_b[l]; U = t@Wi; V = t@Wj.
// 8 nodes per block, 256 threads; thread = (n_half, h).
__global__ __launch_bounds__(256) void k_tuv(const float* __restrict__ hbuf,
                     const float* __restrict__ fc_w, const float* __restrict__ fc_b,
                     const float* __restrict__ attn_w,
                     float* __restrict__ t, float* __restrict__ U, float* __restrict__ V, int l){
    __shared__ float hs[8][HD];
    __shared__ float ts[8][HD];
    int n0 = blockIdx.x * 8;
    int tid = threadIdx.x;
    for (int i = tid; i < 8*HD; i += 256)
        hs[i >> 7][i & (HD-1)] = hbuf[(n0 + (i >> 7))*HD + (i & (HD-1))];
    __syncthreads();
    int hh  = tid & (HD-1);
    int nb2 = tid >> 7;                    // 0 or 1
    const float* Wt = fc_w + l*HD*HD;
    float bias = fc_b[l*HD + hh];
    float acc0 = bias, acc1 = bias, acc2 = bias, acc3 = bias;
    for (int k = 0; k < HD; k++){
        float wv = Wt[k*HD + hh];
        acc0 += hs[nb2  ][k]*wv;
        acc1 += hs[nb2+2][k]*wv;
        acc2 += hs[nb2+4][k]*wv;
        acc3 += hs[nb2+6][k]*wv;
    }
    ts[nb2  ][hh] = acc0;  t[(n0+nb2  )*HD+hh] = acc0;
    ts[nb2+2][hh] = acc1;  t[(n0+nb2+2)*HD+hh] = acc1;
    ts[nb2+4][hh] = acc2;  t[(n0+nb2+4)*HD+hh] = acc2;
    ts[nb2+6][hh] = acc3;  t[(n0+nb2+6)*HD+hh] = acc3;
    __syncthreads();
    const float* Wi = attn_w + l*272*HD;
    const float* Wj = Wi + HD*HD;
    float u0=0,u1=0,u2=0,u3=0, v0=0,v1=0,v2=0,v3=0;
    for (int k = 0; k < HD; k++){
        float wi = Wi[k*HD + hh];
        float wj = Wj[k*HD + hh];
        float t0 = ts[nb2  ][k], t1 = ts[nb2+2][k], t2 = ts[nb2+4][k], t3 = ts[nb2+6][k];
        u0 += t0*wi; u1 += t1*wi; u2 += t2*wi; u3 += t3*wi;
        v0 += t0*wj; v1 += t1*wj; v2 += t2*wj; v3 += t3*wj;
    }
    U[(n0+nb2  )*HD+hh] = u0;  V[(n0+nb2  )*HD+hh] = v0;
    U[(n0+nb2+2)*HD+hh] = u1;  V[(n0+nb2+2)*HD+hh] = v1;
    U[(n0+nb2+4)*HD+hh] = u2;  V[(n0+nb2+4)*HD+hh] = v2;
    U[(n0+nb2+6)*HD+hh] = u3;  V[(n0+nb2+6)*HD+hh] = v3;
}

// Per destination node i (one block, 128 threads = channels):
// online softmax over the 101 sources j, weighted sum of t[j,:], residual add.
__global__ __launch_bounds__(128) void k_attn(const float* __restrict__ U, const float* __restrict__ V,
                      const float* __restrict__ t, const float* __restrict__ eai,
                      const float* __restrict__ c1, const float* __restrict__ dv,
                      float* __restrict__ hbuf, int l, float* __restrict__ outp){
    int ig = blockIdx.x;
    int b = ig / NPER, i = ig - b*NPER;
    int h = threadIdx.x;
    float u   = U[ig*HD + h];
    float c1h = c1[l*HD + h];
    float dd  = dv[l*HD + h];
    const float* Vb = V + (b*NPER)*HD;
    const float* tb = t + (b*NPER)*HD;
    const float* eb = eai + b*PERB + i;
    float m = -INFINITY, s = 0.f, acc = 0.f;
    for (int j = 0; j < NPER; j++){
        float es = eb[j*NPER];
        float z = u + Vb[j*HD + h] + es*c1h + dd;
        z = (z >= 0.f) ? z : SLOPE*z;
        float nm = fmaxf(m, z);
        float so = __expf(m - nm);     // expf(-inf)=0 on first iter
        float wz = __expf(z - nm);
        float tj = tb[j*HD + h];
        s   = s*so + wz;
        acc = acc*so + wz*tj;
        m = nm;
    }
    float res = hbuf[ig*HD + h] + acc/(s + 1e-16f);
    hbuf[ig*HD + h] = res;
    if (outp) outp[ig*HD + h] = res;
}

extern "C" void kernel_launch(void* const* d_in, const int* in_sizes, int n_in,
                              void* d_out, int out_size, void* d_ws, size_t ws_size,
                              hipStream_t stream) {
    const float* x      = (const float*)d_in[0];
    const float* demand = (const float*)d_in[1];
    const float* eai    = (const float*)d_in[2];
    // d_in[3] edge_index: known constant structure, unused
    const float* fnw = (const float*)d_in[4];
    const float* fnb = (const float*)d_in[5];
    const float* bng = (const float*)d_in[6];
    const float* bnb = (const float*)d_in[7];
    const float* few = (const float*)d_in[8];
    // d_in[9] fc_edge_b cancels in BatchNorm
    const float* beg = (const float*)d_in[10];
    const float* beb = (const float*)d_in[11];
    const float* fcw = (const float*)d_in[12];
    const float* fcb = (const float*)d_in[13];
    const float* aw  = (const float*)d_in[14];
    const float* ab  = (const float*)d_in[15];
    float* out = (float*)d_out;

    float* w     = (float*)d_ws;
    float* hbuf  = w;
    float* tbuf  = w + (size_t)NN*HD;
    float* Ubuf  = w + (size_t)2*NN*HD;
    float* Vbuf  = w + (size_t)3*NN*HD;
    float* stats = w + (size_t)4*NN*HD;   // 4 floats
    float* c1    = stats + 4;             // 3*128
    float* dv    = c1 + 3*HD;             // 3*128

    hipLaunchKernelGGL(k_zero, dim3(1), dim3(64), 0, stream, stats, 4);
    hipLaunchKernelGGL(k_reduce_eai, dim3(256), dim3(256), 0, stream, eai, stats);
    hipLaunchKernelGGL(k_setup, dim3(1), dim3(HD), 0, stream, stats, few, beg, beb, aw, ab, c1, dv);
    hipLaunchKernelGGL(k_node_bn, dim3(HD), dim3(256), 0, stream, x, demand, fnw, fnb, bng, bnb, hbuf);
    for (int l = 0; l < 3; l++){
        hipLaunchKernelGGL(k_tuv, dim3(NN/8), dim3(256), 0, stream,
                           hbuf, fcw, fcb, aw, tbuf, Ubuf, Vbuf, l);
        hipLaunchKernelGGL(k_attn, dim3(NN), dim3(HD), 0, stream,
                           Ubuf, Vbuf, tbuf, eai, c1, dv, hbuf, l, (l == 2) ? out : (float*)nullptr);
    }
}

// Round 2
// 229.299 us; speedup vs baseline: 1.0597x; 1.0597x over previous
//
#include <hip/hip_runtime.h>
#include <math.h>

#define NN   6464      // total nodes
#define NPER 101
#define HD   128
#define HE   16
#define NE   652864    // 64*101*101
#define PERB 10201     // 101*101
#define EPSB 1e-5f
#define SLOPE 0.2f
#define TI   4         // dest nodes per block in attention
#define NBLK 26        // ceil(101/4)

__global__ void k_zero(float* p, int n){
    int i = blockIdx.x*blockDim.x + threadIdx.x;
    if (i < n) p[i] = 0.f;
}

__global__ void k_reduce_eai(const float* __restrict__ eai, float* __restrict__ stats){
    __shared__ float ls[256], ls2[256];
    float s = 0.f, s2 = 0.f;
    for (int i = blockIdx.x*256 + threadIdx.x; i < NE; i += gridDim.x*256){
        float v = eai[i]; s += v; s2 += v*v;
    }
    int tid = threadIdx.x;
    ls[tid] = s; ls2[tid] = s2; __syncthreads();
    for (int o = 128; o > 0; o >>= 1){
        if (tid < o){ ls[tid] += ls[tid+o]; ls2[tid] += ls2[tid+o]; }
        __syncthreads();
    }
    if (tid == 0){ atomicAdd(&stats[0], ls[0]); atomicAdd(&stats[1], ls2[0]); }
}

// Build per-layer c1[h], d[h] from edge-attr batch stats:
//   ea_bn[e,k] = eai[e]*A[k] + B[k];  ea_bn @ We = eai*c1 + c2;  d = c2 + attn_b
__global__ void k_setup(const float* __restrict__ stats, const float* __restrict__ few,
                        const float* __restrict__ beg, const float* __restrict__ beb,
                        const float* __restrict__ attn_w, const float* __restrict__ attn_b,
                        float* __restrict__ c1, float* __restrict__ dv){
    __shared__ float sA[HE], sB[HE];
    int tid = threadIdx.x;                 // 128 threads = h
    float mean = stats[0] * (1.f/NE);
    float var  = stats[1] * (1.f/NE) - mean*mean;
    if (tid < HE){
        float w = few[tid];
        float a = w * rsqrtf(var*w*w + EPSB) * beg[tid];
        sA[tid] = a; sB[tid] = beb[tid] - mean*a;
    }
    __syncthreads();
    for (int l = 0; l < 3; l++){
        const float* W = attn_w + (l*272 + 256)*HD;   // We rows (256..271)
        float a1 = 0.f, a2 = 0.f;
        for (int k = 0; k < HE; k++){
            float wv = W[k*HD + tid];
            a1 += sA[k]*wv; a2 += sB[k]*wv;
        }
        c1[l*HD + tid] = a1;
        dv[l*HD + tid] = a2 + attn_b[l*HD + tid];
    }
}

// h0 = [x,demand] @ fc_node_w + b, then training-mode BatchNorm over all N rows.
__global__ __launch_bounds__(256) void k_node_bn(const float* __restrict__ x, const float* __restrict__ demand,
                          const float* __restrict__ w, const float* __restrict__ b,
                          const float* __restrict__ g, const float* __restrict__ beta,
                          float* __restrict__ hbuf){
    int k = blockIdx.x, tid = threadIdx.x;
    float w0 = w[k], w1 = w[HD+k], w2 = w[2*HD+k], bb = b[k];
    float s = 0.f, s2 = 0.f;
    for (int n = tid; n < NN; n += 256){
        float p = x[2*n]*w0 + x[2*n+1]*w1 + demand[n]*w2 + bb;
        s += p; s2 += p*p;
    }
    __shared__ float ls[256], ls2[256];
    ls[tid] = s; ls2[tid] = s2; __syncthreads();
    for (int o = 128; o > 0; o >>= 1){
        if (tid < o){ ls[tid] += ls[tid+o]; ls2[tid] += ls2[tid+o]; }
        __syncthreads();
    }
    __shared__ float smu, srs;
    if (tid == 0){
        float mu = ls[0]*(1.f/NN);
        float var = ls2[0]*(1.f/NN) - mu*mu;
        smu = mu; srs = rsqrtf(var + EPSB);
    }
    __syncthreads();
    float mu = smu, rs = srs, gg = g[k], be = beta[k];
    for (int n = tid; n < NN; n += 256){
        float p = x[2*n]*w0 + x[2*n+1]*w1 + demand[n]*w2 + bb;
        hbuf[n*HD + k] = (p - mu)*rs*gg + be;
    }
}

// Fused per-node GEMMs: t = h@fc_w[l]+fc_b[l]; U = t@Wi; V = t@Wj.
__global__ __launch_bounds__(256) void k_tuv(const float* __restrict__ hbuf,
                     const float* __restrict__ fc_w, const float* __restrict__ fc_b,
                     const float* __restrict__ attn_w,
                     float* __restrict__ t, float* __restrict__ U, float* __restrict__ V, int l){
    __shared__ float hs[8][HD];
    __shared__ float ts[8][HD];
    int n0 = blockIdx.x * 8;
    int tid = threadIdx.x;
    for (int i = tid; i < 8*HD; i += 256)
        hs[i >> 7][i & (HD-1)] = hbuf[(n0 + (i >> 7))*HD + (i & (HD-1))];
    __syncthreads();
    int hh  = tid & (HD-1);
    int nb2 = tid >> 7;                    // 0 or 1
    const float* Wt = fc_w + l*HD*HD;
    float bias = fc_b[l*HD + hh];
    float acc0 = bias, acc1 = bias, acc2 = bias, acc3 = bias;
    for (int k = 0; k < HD; k++){
        float wv = Wt[k*HD + hh];
        acc0 += hs[nb2  ][k]*wv;
        acc1 += hs[nb2+2][k]*wv;
        acc2 += hs[nb2+4][k]*wv;
        acc3 += hs[nb2+6][k]*wv;
    }
    ts[nb2  ][hh] = acc0;  t[(n0+nb2  )*HD+hh] = acc0;
    ts[nb2+2][hh] = acc1;  t[(n0+nb2+2)*HD+hh] = acc1;
    ts[nb2+4][hh] = acc2;  t[(n0+nb2+4)*HD+hh] = acc2;
    ts[nb2+6][hh] = acc3;  t[(n0+nb2+6)*HD+hh] = acc3;
    __syncthreads();
    const float* Wi = attn_w + l*272*HD;
    const float* Wj = Wi + HD*HD;
    float u0=0,u1=0,u2=0,u3=0, v0=0,v1=0,v2=0,v3=0;
    for (int k = 0; k < HD; k++){
        float wi = Wi[k*HD + hh];
        float wj = Wj[k*HD + hh];
        float t0 = ts[nb2  ][k], t1 = ts[nb2+2][k], t2 = ts[nb2+4][k], t3 = ts[nb2+6][k];
        u0 += t0*wi; u1 += t1*wi; u2 += t2*wi; u3 += t3*wi;
        v0 += t0*wj; v1 += t1*wj; v2 += t2*wj; v3 += t3*wj;
    }
    U[(n0+nb2  )*HD+hh] = u0;  V[(n0+nb2  )*HD+hh] = v0;
    U[(n0+nb2+2)*HD+hh] = u1;  V[(n0+nb2+2)*HD+hh] = v1;
    U[(n0+nb2+4)*HD+hh] = u2;  V[(n0+nb2+4)*HD+hh] = v2;
    U[(n0+nb2+6)*HD+hh] = u3;  V[(n0+nb2+6)*HD+hh] = v3;
}

// Attention: TI dest nodes per block, 128 threads = channels.
// Softmax without max-subtraction (logits structurally bounded, |z| < ~15):
// out[i,h] = sum_j exp(z) * t[j,h] / sum_j exp(z);  z = leaky(U[i,h]+V[j,h]+es*c1h+d)
__global__ __launch_bounds__(128) void k_attn2(const float* __restrict__ U, const float* __restrict__ V,
                      const float* __restrict__ t, const float* __restrict__ eai,
                      const float* __restrict__ c1, const float* __restrict__ dv,
                      float* __restrict__ hbuf, int l, float* __restrict__ outp){
    int blk = blockIdx.x;
    int b = blk / NBLK, c = blk - b*NBLK;
    int i0 = c*TI;
    int h = threadIdx.x;
    float c1h = c1[l*HD + h];
    float dd  = dv[l*HD + h];
    int   ib[TI];
    const float* ep[TI];
    float base[TI], s[TI], acc[TI];
    #pragma unroll
    for (int k = 0; k < TI; k++){
        int i = i0 + k; if (i > NPER-1) i = NPER-1;   // clamp tail (stores guarded)
        ib[k]   = b*NPER + i;
        ep[k]   = eai + (size_t)b*PERB + i;
        base[k] = U[(size_t)ib[k]*HD + h] + dd;
        s[k] = 0.f; acc[k] = 0.f;
    }
    const float* Vb = V + (size_t)(b*NPER)*HD + h;
    const float* tb = t + (size_t)(b*NPER)*HD + h;
    #pragma unroll 2
    for (int j = 0; j < NPER; j++){
        float vj = Vb[(size_t)j*HD];
        float tj = tb[(size_t)j*HD];
        #pragma unroll
        for (int k = 0; k < TI; k++){
            float es = ep[k][(size_t)j*NPER];
            float z  = fmaf(es, c1h, base[k] + vj);
            z = fmaxf(z, SLOPE*z);                    // leaky_relu
            float w = __expf(z);
            s[k]  += w;
            acc[k] = fmaf(w, tj, acc[k]);
        }
    }
    float res[TI];
    #pragma unroll
    for (int k = 0; k < TI; k++)
        res[k] = hbuf[(size_t)ib[k]*HD + h] + acc[k]/(s[k] + 1e-16f);
    #pragma unroll
    for (int k = 0; k < TI; k++){
        if (i0 + k < NPER){
            hbuf[(size_t)ib[k]*HD + h] = res[k];
            if (outp) outp[(size_t)ib[k]*HD + h] = res[k];
        }
    }
}

extern "C" void kernel_launch(void* const* d_in, const int* in_sizes, int n_in,
                              void* d_out, int out_size, void* d_ws, size_t ws_size,
                              hipStream_t stream) {
    const float* x      = (const float*)d_in[0];
    const float* demand = (const float*)d_in[1];
    const float* eai    = (const float*)d_in[2];
    // d_in[3] edge_index: known constant structure, unused
    const float* fnw = (const float*)d_in[4];
    const float* fnb = (const float*)d_in[5];
    const float* bng = (const float*)d_in[6];
    const float* bnb = (const float*)d_in[7];
    const float* few = (const float*)d_in[8];
    // d_in[9] fc_edge_b cancels in BatchNorm
    const float* beg = (const float*)d_in[10];
    const float* beb = (const float*)d_in[11];
    const float* fcw = (const float*)d_in[12];
    const float* fcb = (const float*)d_in[13];
    const float* aw  = (const float*)d_in[14];
    const float* ab  = (const float*)d_in[15];
    float* out = (float*)d_out;

    float* w     = (float*)d_ws;
    float* hbuf  = w;
    float* tbuf  = w + (size_t)NN*HD;
    float* Ubuf  = w + (size_t)2*NN*HD;
    float* Vbuf  = w + (size_t)3*NN*HD;
    float* stats = w + (size_t)4*NN*HD;   // 4 floats
    float* c1    = stats + 4;             // 3*128
    float* dv    = c1 + 3*HD;             // 3*128

    hipLaunchKernelGGL(k_zero, dim3(1), dim3(64), 0, stream, stats, 4);
    hipLaunchKernelGGL(k_reduce_eai, dim3(256), dim3(256), 0, stream, eai, stats);
    hipLaunchKernelGGL(k_setup, dim3(1), dim3(HD), 0, stream, stats, few, beg, beb, aw, ab, c1, dv);
    hipLaunchKernelGGL(k_node_bn, dim3(HD), dim3(256), 0, stream, x, demand, fnw, fnb, bng, bnb, hbuf);
    for (int l = 0; l < 3; l++){
        hipLaunchKernelGGL(k_tuv, dim3(NN/8), dim3(256), 0, stream,
                           hbuf, fcw, fcb, aw, tbuf, Ubuf, Vbuf, l);
        hipLaunchKernelGGL(k_attn2, dim3(64*NBLK), dim3(HD), 0, stream,
                           Ubuf, Vbuf, tbuf, eai, c1, dv, hbuf, l, (l == 2) ? out : (float*)nullptr);
    }
}

// Round 3
// 224.609 us; speedup vs baseline: 1.0818x; 1.0209x over previous
//
#include <hip/hip_runtime.h>
#include <math.h>

#define NN   6464      // total nodes
#define NPER 101
#define HD   128
#define HE   16
#define NE   652864    // 64*101*101
#define PERB 10201     // 101*101
#define EPSB 1e-5f
#define SLOPE 0.2f
#define TI   8         // dest nodes per block in attention
#define NBLK 13        // ceil(101/8)

__global__ void k_zero(float* p, int n){
    int i = blockIdx.x*blockDim.x + threadIdx.x;
    if (i < n) p[i] = 0.f;
}

__global__ void k_reduce_eai(const float* __restrict__ eai, float* __restrict__ stats){
    __shared__ float ls[256], ls2[256];
    float s = 0.f, s2 = 0.f;
    for (int i = blockIdx.x*256 + threadIdx.x; i < NE; i += gridDim.x*256){
        float v = eai[i]; s += v; s2 += v*v;
    }
    int tid = threadIdx.x;
    ls[tid] = s; ls2[tid] = s2; __syncthreads();
    for (int o = 128; o > 0; o >>= 1){
        if (tid < o){ ls[tid] += ls[tid+o]; ls2[tid] += ls2[tid+o]; }
        __syncthreads();
    }
    if (tid == 0){ atomicAdd(&stats[0], ls[0]); atomicAdd(&stats[1], ls2[0]); }
}

// Build per-layer c1[h], d[h] from edge-attr batch stats:
//   ea_bn[e,k] = eai[e]*A[k] + B[k];  ea_bn @ We = eai*c1 + c2;  d = c2 + attn_b
__global__ void k_setup(const float* __restrict__ stats, const float* __restrict__ few,
                        const float* __restrict__ beg, const float* __restrict__ beb,
                        const float* __restrict__ attn_w, const float* __restrict__ attn_b,
                        float* __restrict__ c1, float* __restrict__ dv){
    __shared__ float sA[HE], sB[HE];
    int tid = threadIdx.x;                 // 128 threads = h
    float mean = stats[0] * (1.f/NE);
    float var  = stats[1] * (1.f/NE) - mean*mean;
    if (tid < HE){
        float w = few[tid];
        float a = w * rsqrtf(var*w*w + EPSB) * beg[tid];
        sA[tid] = a; sB[tid] = beb[tid] - mean*a;
    }
    __syncthreads();
    for (int l = 0; l < 3; l++){
        const float* W = attn_w + (l*272 + 256)*HD;   // We rows (256..271)
        float a1 = 0.f, a2 = 0.f;
        for (int k = 0; k < HE; k++){
            float wv = W[k*HD + tid];
            a1 += sA[k]*wv; a2 += sB[k]*wv;
        }
        c1[l*HD + tid] = a1;
        dv[l*HD + tid] = a2 + attn_b[l*HD + tid];
    }
}

// h0 = [x,demand] @ fc_node_w + b, then training-mode BatchNorm over all N rows.
__global__ __launch_bounds__(256) void k_node_bn(const float* __restrict__ x, const float* __restrict__ demand,
                          const float* __restrict__ w, const float* __restrict__ b,
                          const float* __restrict__ g, const float* __restrict__ beta,
                          float* __restrict__ hbuf){
    int k = blockIdx.x, tid = threadIdx.x;
    float w0 = w[k], w1 = w[HD+k], w2 = w[2*HD+k], bb = b[k];
    float s = 0.f, s2 = 0.f;
    for (int n = tid; n < NN; n += 256){
        float p = x[2*n]*w0 + x[2*n+1]*w1 + demand[n]*w2 + bb;
        s += p; s2 += p*p;
    }
    __shared__ float ls[256], ls2[256];
    ls[tid] = s; ls2[tid] = s2; __syncthreads();
    for (int o = 128; o > 0; o >>= 1){
        if (tid < o){ ls[tid] += ls[tid+o]; ls2[tid] += ls2[tid+o]; }
        __syncthreads();
    }
    __shared__ float smu, srs;
    if (tid == 0){
        float mu = ls[0]*(1.f/NN);
        float var = ls2[0]*(1.f/NN) - mu*mu;
        smu = mu; srs = rsqrtf(var + EPSB);
    }
    __syncthreads();
    float mu = smu, rs = srs, gg = g[k], be = beta[k];
    for (int n = tid; n < NN; n += 256){
        float p = x[2*n]*w0 + x[2*n+1]*w1 + demand[n]*w2 + bb;
        hbuf[n*HD + k] = (p - mu)*rs*gg + be;
    }
}

// Fused per-node GEMMs: t = h@fc_w[l]+fc_b[l]; U = t@Wi; V = t@Wj.
__global__ __launch_bounds__(256) void k_tuv(const float* __restrict__ hbuf,
                     const float* __restrict__ fc_w, const float* __restrict__ fc_b,
                     const float* __restrict__ attn_w,
                     float* __restrict__ t, float* __restrict__ U, float* __restrict__ V, int l){
    __shared__ float hs[8][HD];
    __shared__ float ts[8][HD];
    int n0 = blockIdx.x * 8;
    int tid = threadIdx.x;
    for (int i = tid; i < 8*HD; i += 256)
        hs[i >> 7][i & (HD-1)] = hbuf[(n0 + (i >> 7))*HD + (i & (HD-1))];
    __syncthreads();
    int hh  = tid & (HD-1);
    int nb2 = tid >> 7;                    // 0 or 1
    const float* Wt = fc_w + l*HD*HD;
    float bias = fc_b[l*HD + hh];
    float acc0 = bias, acc1 = bias, acc2 = bias, acc3 = bias;
    for (int k = 0; k < HD; k++){
        float wv = Wt[k*HD + hh];
        acc0 += hs[nb2  ][k]*wv;
        acc1 += hs[nb2+2][k]*wv;
        acc2 += hs[nb2+4][k]*wv;
        acc3 += hs[nb2+6][k]*wv;
    }
    ts[nb2  ][hh] = acc0;  t[(n0+nb2  )*HD+hh] = acc0;
    ts[nb2+2][hh] = acc1;  t[(n0+nb2+2)*HD+hh] = acc1;
    ts[nb2+4][hh] = acc2;  t[(n0+nb2+4)*HD+hh] = acc2;
    ts[nb2+6][hh] = acc3;  t[(n0+nb2+6)*HD+hh] = acc3;
    __syncthreads();
    const float* Wi = attn_w + l*272*HD;
    const float* Wj = Wi + HD*HD;
    float u0=0,u1=0,u2=0,u3=0, v0=0,v1=0,v2=0,v3=0;
    for (int k = 0; k < HD; k++){
        float wi = Wi[k*HD + hh];
        float wj = Wj[k*HD + hh];
        float t0 = ts[nb2  ][k], t1 = ts[nb2+2][k], t2 = ts[nb2+4][k], t3 = ts[nb2+6][k];
        u0 += t0*wi; u1 += t1*wi; u2 += t2*wi; u3 += t3*wi;
        v0 += t0*wj; v1 += t1*wj; v2 += t2*wj; v3 += t3*wj;
    }
    U[(n0+nb2  )*HD+hh] = u0;  V[(n0+nb2  )*HD+hh] = v0;
    U[(n0+nb2+2)*HD+hh] = u1;  V[(n0+nb2+2)*HD+hh] = v1;
    U[(n0+nb2+4)*HD+hh] = u2;  V[(n0+nb2+4)*HD+hh] = v2;
    U[(n0+nb2+6)*HD+hh] = u3;  V[(n0+nb2+6)*HD+hh] = v3;
}

// Attention v3: TI=8 dest nodes per block, 256 threads = (jg, h).
// eai slab staged in LDS; j-loop split across jg halves; partials combined in LDS.
// Softmax without max-subtraction (logits structurally bounded).
__global__ __launch_bounds__(256) void k_attn3(const float* __restrict__ U, const float* __restrict__ V,
                      const float* __restrict__ t, const float* __restrict__ eai,
                      const float* __restrict__ c1, const float* __restrict__ dv,
                      float* __restrict__ hbuf, int l, float* __restrict__ outp){
    __shared__ float es_s[NPER][TI];
    __shared__ float ps[TI][HD], pa[TI][HD];
    int blk = blockIdx.x;
    int b = blk / NBLK, c = blk - b*NBLK;
    int i0 = c*TI;
    int tid = threadIdx.x;
    int h  = tid & (HD-1);
    int jg = tid >> 7;                     // 0 or 1

    // stage edge-attr slab: es_s[j][k] = eai[b,j,i0+k]
    for (int idx = tid; idx < NPER*TI; idx += 256){
        int j = idx >> 3, k = idx & 7;
        int i = i0 + k; if (i > NPER-1) i = NPER-1;
        es_s[j][k] = eai[(size_t)b*PERB + (size_t)j*NPER + i];
    }

    float c1h = c1[l*HD + h];
    float dd  = dv[l*HD + h];
    int   ib[TI];
    float base[TI], s[TI], acc[TI];
    #pragma unroll
    for (int k = 0; k < TI; k++){
        int i = i0 + k; if (i > NPER-1) i = NPER-1;   // clamp tail (stores guarded)
        ib[k]   = b*NPER + i;
        base[k] = U[(size_t)ib[k]*HD + h] + dd;
        s[k] = 0.f; acc[k] = 0.f;
    }
    __syncthreads();

    const float* Vb = V + (size_t)(b*NPER)*HD + h;
    const float* tb = t + (size_t)(b*NPER)*HD + h;
    int j0 = jg ? 51 : 0;
    int j1 = jg ? NPER : 51;
    float vj = Vb[(size_t)j0*HD];
    float tj = tb[(size_t)j0*HD];
    for (int j = j0; j < j1; j++){
        float vn = 0.f, tn = 0.f;
        if (j + 1 < j1){                   // prefetch next row (uniform branch)
            vn = Vb[(size_t)(j+1)*HD];
            tn = tb[(size_t)(j+1)*HD];
        }
        #pragma unroll
        for (int k = 0; k < TI; k++){
            float z = fmaf(es_s[j][k], c1h, base[k] + vj);
            z = fmaxf(z, SLOPE*z);         // leaky_relu
            float w = __expf(z);
            s[k]  += w;
            acc[k] = fmaf(w, tj, acc[k]);
        }
        vj = vn; tj = tn;
    }

    if (jg){
        #pragma unroll
        for (int k = 0; k < TI; k++){ ps[k][h] = s[k]; pa[k][h] = acc[k]; }
    }
    __syncthreads();
    if (!jg){
        #pragma unroll
        for (int k = 0; k < TI; k++){
            float st = s[k] + ps[k][h];
            float at = acc[k] + pa[k][h];
            float res = hbuf[(size_t)ib[k]*HD + h] + at/(st + 1e-16f);
            if (i0 + k < NPER){
                hbuf[(size_t)ib[k]*HD + h] = res;
                if (outp) outp[(size_t)ib[k]*HD + h] = res;
            }
        }
    }
}

extern "C" void kernel_launch(void* const* d_in, const int* in_sizes, int n_in,
                              void* d_out, int out_size, void* d_ws, size_t ws_size,
                              hipStream_t stream) {
    const float* x      = (const float*)d_in[0];
    const float* demand = (const float*)d_in[1];
    const float* eai    = (const float*)d_in[2];
    // d_in[3] edge_index: known constant structure, unused
    const float* fnw = (const float*)d_in[4];
    const float* fnb = (const float*)d_in[5];
    const float* bng = (const float*)d_in[6];
    const float* bnb = (const float*)d_in[7];
    const float* few = (const float*)d_in[8];
    // d_in[9] fc_edge_b cancels in BatchNorm
    const float* beg = (const float*)d_in[10];
    const float* beb = (const float*)d_in[11];
    const float* fcw = (const float*)d_in[12];
    const float* fcb = (const float*)d_in[13];
    const float* aw  = (const float*)d_in[14];
    const float* ab  = (const float*)d_in[15];
    float* out = (float*)d_out;

    float* w     = (float*)d_ws;
    float* hbuf  = w;
    float* tbuf  = w + (size_t)NN*HD;
    float* Ubuf  = w + (size_t)2*NN*HD;
    float* Vbuf  = w + (size_t)3*NN*HD;
    float* stats = w + (size_t)4*NN*HD;   // 4 floats
    float* c1    = stats + 4;             // 3*128
    float* dv    = c1 + 3*HD;             // 3*128

    hipLaunchKernelGGL(k_zero, dim3(1), dim3(64), 0, stream, stats, 4);
    hipLaunchKernelGGL(k_reduce_eai, dim3(256), dim3(256), 0, stream, eai, stats);
    hipLaunchKernelGGL(k_setup, dim3(1), dim3(HD), 0, stream, stats, few, beg, beb, aw, ab, c1, dv);
    hipLaunchKernelGGL(k_node_bn, dim3(HD), dim3(256), 0, stream, x, demand, fnw, fnb, bng, bnb, hbuf);
    for (int l = 0; l < 3; l++){
        hipLaunchKernelGGL(k_tuv, dim3(NN/8), dim3(256), 0, stream,
                           hbuf, fcw, fcb, aw, tbuf, Ubuf, Vbuf, l);
        hipLaunchKernelGGL(k_attn3, dim3(64*NBLK), dim3(256), 0, stream,
                           Ubuf, Vbuf, tbuf, eai, c1, dv, hbuf, l, (l == 2) ? out : (float*)nullptr);
    }
}

// Round 4
// 192.910 us; speedup vs baseline: 1.2596x; 1.1643x over previous
//
#include <hip/hip_runtime.h>
#include <math.h>

#define NN   6464      // total nodes
#define NPER 101
#define HD   128
#define HE   16
#define NE   652864    // 64*101*101
#define PERB 10201     // 101*101
#define EPSB 1e-5f
#define SLOPE 0.2f
#define TI   4         // dest nodes per attention block
#define NBLK 26        // ceil(101/4)
#define L2E  1.44269504088896340736f

__global__ void k_zero(float* p, int n){
    int i = blockIdx.x*blockDim.x + threadIdx.x;
    if (i < n) p[i] = 0.f;
}

__global__ void k_reduce_eai(const float* __restrict__ eai, float* __restrict__ stats){
    __shared__ float ls[256], ls2[256];
    float s = 0.f, s2 = 0.f;
    for (int i = blockIdx.x*256 + threadIdx.x; i < NE; i += gridDim.x*256){
        float v = eai[i]; s += v; s2 += v*v;
    }
    int tid = threadIdx.x;
    ls[tid] = s; ls2[tid] = s2; __syncthreads();
    for (int o = 128; o > 0; o >>= 1){
        if (tid < o){ ls[tid] += ls[tid+o]; ls2[tid] += ls2[tid+o]; }
        __syncthreads();
    }
    if (tid == 0){ atomicAdd(&stats[0], ls[0]); atomicAdd(&stats[1], ls2[0]); }
}

// c1[h], dv[h] per layer from edge-attr batch stats (both pre-scaled by L2E).
__global__ void k_setup(const float* __restrict__ stats, const float* __restrict__ few,
                        const float* __restrict__ beg, const float* __restrict__ beb,
                        const float* __restrict__ attn_w, const float* __restrict__ attn_b,
                        float* __restrict__ c1, float* __restrict__ dv){
    __shared__ float sA[HE], sB[HE];
    int tid = threadIdx.x;                 // 128 threads = h
    float mean = stats[0] * (1.f/NE);
    float var  = stats[1] * (1.f/NE) - mean*mean;
    if (tid < HE){
        float w = few[tid];
        float a = w * rsqrtf(var*w*w + EPSB) * beg[tid];
        sA[tid] = a; sB[tid] = beb[tid] - mean*a;
    }
    __syncthreads();
    for (int l = 0; l < 3; l++){
        const float* W = attn_w + (l*272 + 256)*HD;   // We rows (256..271)
        float a1 = 0.f, a2 = 0.f;
        for (int k = 0; k < HE; k++){
            float wv = W[k*HD + tid];
            a1 += sA[k]*wv; a2 += sB[k]*wv;
        }
        c1[l*HD + tid] = a1 * L2E;
        dv[l*HD + tid] = (a2 + attn_b[l*HD + tid]) * L2E;
    }
}

// Composite matrices: CWi = (fc_w[l] @ Wi)*L2E, CWj = (fc_w[l] @ Wj)*L2E.
// Row r==128 handles the bias row: dv += (fc_b@Wi + fc_b@Wj)*L2E (runs after k_setup).
__global__ __launch_bounds__(128) void k_comp(const float* __restrict__ fc_w, const float* __restrict__ fc_b,
                     const float* __restrict__ attn_w, float* __restrict__ CW, float* __restrict__ dv){
    int blk = blockIdx.x;
    int l = blk / 129, r = blk - l*129;
    int hh = threadIdx.x;
    const float* Wi = attn_w + (size_t)l*272*HD;
    const float* Wj = Wi + HD*HD;
    const float* Fr = (r < HD) ? (fc_w + (size_t)l*HD*HD + (size_t)r*HD) : (fc_b + l*HD);
    float ai = 0.f, aj = 0.f;
    for (int m = 0; m < HD; m++){
        float f = Fr[m];
        ai = fmaf(f, Wi[m*HD + hh], ai);
        aj = fmaf(f, Wj[m*HD + hh], aj);
    }
    if (r < HD){
        CW[((size_t)l*2    )*HD*HD + (size_t)r*HD + hh] = ai * L2E;
        CW[((size_t)l*2 + 1)*HD*HD + (size_t)r*HD + hh] = aj * L2E;
    } else {
        dv[l*HD + hh] += (ai + aj) * L2E;
    }
}

// h0 = [x,demand] @ fc_node_w + b, training-mode BatchNorm over all N rows.
__global__ __launch_bounds__(256) void k_node_bn(const float* __restrict__ x, const float* __restrict__ demand,
                          const float* __restrict__ w, const float* __restrict__ b,
                          const float* __restrict__ g, const float* __restrict__ beta,
                          float* __restrict__ hbuf){
    int k = blockIdx.x, tid = threadIdx.x;
    float w0 = w[k], w1 = w[HD+k], w2 = w[2*HD+k], bb = b[k];
    float s = 0.f, s2 = 0.f;
    for (int n = tid; n < NN; n += 256){
        float p = x[2*n]*w0 + x[2*n+1]*w1 + demand[n]*w2 + bb;
        s += p; s2 += p*p;
    }
    __shared__ float ls[256], ls2[256];
    ls[tid] = s; ls2[tid] = s2; __syncthreads();
    for (int o = 128; o > 0; o >>= 1){
        if (tid < o){ ls[tid] += ls[tid+o]; ls2[tid] += ls2[tid+o]; }
        __syncthreads();
    }
    __shared__ float smu, srs;
    if (tid == 0){
        float mu = ls[0]*(1.f/NN);
        float var = ls2[0]*(1.f/NN) - mu*mu;
        smu = mu; srs = rsqrtf(var + EPSB);
    }
    __syncthreads();
    float mu = smu, rs = srs, gg = g[k], be = beta[k];
    for (int n = tid; n < NN; n += 256){
        float p = x[2*n]*w0 + x[2*n+1]*w1 + demand[n]*w2 + bb;
        hbuf[n*HD + k] = (p - mu)*rs*gg + be;
    }
}

// One pass: t = h@F + fc_b;  U = h@CWi (L2E-scaled, bias folded into dv);  V = h@CWj.
// 8 nodes/block, 256 threads = (ng, hh); hs transposed [k][node] for b128 broadcast reads.
__global__ __launch_bounds__(256) void k_tuv3(const float* __restrict__ hbuf,
                     const float* __restrict__ fc_w, const float* __restrict__ fc_b,
                     const float* __restrict__ CW,
                     float* __restrict__ t, float* __restrict__ U, float* __restrict__ V, int l){
    __shared__ float hs[HD][12];           // [k][node], pad to 12 (48B rows, 16B-aligned quads)
    int n0 = blockIdx.x * 8;
    int tid = threadIdx.x;
    for (int idx = tid; idx < 8*HD; idx += 256){
        int n = idx >> 7, k = idx & (HD-1);
        hs[k][n] = hbuf[(size_t)(n0+n)*HD + k];
    }
    __syncthreads();
    int hh = tid & (HD-1), ng = tid >> 7;  // nodes 4ng..4ng+3
    const float* Ft = fc_w + (size_t)l*HD*HD + hh;
    const float* Wi = CW + (size_t)l*2*HD*HD + hh;
    const float* Wj = Wi + HD*HD;
    float bias = fc_b[l*HD + hh];
    float t0=bias,t1=bias,t2=bias,t3=bias;
    float u0=0,u1=0,u2=0,u3=0, v0=0,v1=0,v2=0,v3=0;
    #pragma unroll 4
    for (int k = 0; k < HD; k++){
        float wt = Ft[(size_t)k*HD];
        float wi = Wi[(size_t)k*HD];
        float wj = Wj[(size_t)k*HD];
        float4 hv = *(const float4*)&hs[k][ng*4];
        t0 = fmaf(hv.x, wt, t0); t1 = fmaf(hv.y, wt, t1);
        t2 = fmaf(hv.z, wt, t2); t3 = fmaf(hv.w, wt, t3);
        u0 = fmaf(hv.x, wi, u0); u1 = fmaf(hv.y, wi, u1);
        u2 = fmaf(hv.z, wi, u2); u3 = fmaf(hv.w, wi, u3);
        v0 = fmaf(hv.x, wj, v0); v1 = fmaf(hv.y, wj, v1);
        v2 = fmaf(hv.z, wj, v2); v3 = fmaf(hv.w, wj, v3);
    }
    size_t nb = (size_t)(n0 + ng*4)*HD + hh;
    t[nb       ] = t0; t[nb +   HD] = t1; t[nb + 2*HD] = t2; t[nb + 3*HD] = t3;
    U[nb       ] = u0; U[nb +   HD] = u1; U[nb + 2*HD] = u2; U[nb + 3*HD] = u3;
    V[nb       ] = v0; V[nb +   HD] = v1; V[nb + 2*HD] = v2; V[nb + 3*HD] = v3;
}

// Attention v4: TI=4 dest nodes, 512 threads = (jg in [0,4), h).
// z pre-scaled by L2E -> bare v_exp_f32. 4-way j-split, partials combined via LDS.
__global__ __launch_bounds__(512) void k_attn4(const float* __restrict__ U, const float* __restrict__ V,
                      const float* __restrict__ t, const float* __restrict__ eai,
                      const float* __restrict__ c1, const float* __restrict__ dv,
                      float* __restrict__ hbuf, int l, float* __restrict__ outp){
    __shared__ float4 es4[NPER];           // es4[j] = eai cols i0..i0+3 at row j
    __shared__ float ps[3][TI][HD], pa[3][TI][HD];
    int blk = blockIdx.x;
    int b = blk / NBLK, c = blk - b*NBLK;
    int i0 = c*TI;
    int tid = threadIdx.x;
    int h  = tid & (HD-1);
    int jg = tid >> 7;                     // 0..3
    for (int idx = tid; idx < NPER*TI; idx += 512){
        int j = idx >> 2, k = idx & 3;
        int i = i0 + k; if (i > NPER-1) i = NPER-1;
        ((float*)&es4[j])[k] = eai[(size_t)b*PERB + (size_t)j*NPER + i];
    }
    float c1h = c1[l*HD + h];
    float dd  = dv[l*HD + h];
    int   ib[TI];
    float base[TI], s[TI], acc[TI];
    #pragma unroll
    for (int k = 0; k < TI; k++){
        int i = i0 + k; if (i > NPER-1) i = NPER-1;
        ib[k]   = b*NPER + i;
        base[k] = U[(size_t)ib[k]*HD + h] + dd;   // already * L2E
        s[k] = 0.f; acc[k] = 0.f;
    }
    __syncthreads();

    const float* Vb = V + (size_t)(b*NPER)*HD + h;
    const float* tb = t + (size_t)(b*NPER)*HD + h;
    int j0 = jg*26;
    int j1 = j0 + 26; if (j1 > NPER) j1 = NPER;
    float vj = Vb[(size_t)j0*HD];
    float tj = tb[(size_t)j0*HD];
    #pragma unroll 2
    for (int j = j0; j < j1; j++){
        int jn = (j+1 < j1) ? j+1 : j;     // branchless next-row prefetch
        float vn = Vb[(size_t)jn*HD];
        float tn = tb[(size_t)jn*HD];
        float4 e4 = es4[j];
        float ev[TI] = {e4.x, e4.y, e4.z, e4.w};
        #pragma unroll
        for (int k = 0; k < TI; k++){
            float z = fmaf(ev[k], c1h, base[k] + vj);
            z = fmaxf(z, SLOPE*z);                   // leaky (commutes with L2E>0)
            float w = __builtin_amdgcn_exp2f(z);     // exp(y) since z = y*log2(e)
            s[k]  += w;
            acc[k] = fmaf(w, tj, acc[k]);
        }
        vj = vn; tj = tn;
    }

    if (jg){
        #pragma unroll
        for (int k = 0; k < TI; k++){ ps[jg-1][k][h] = s[k]; pa[jg-1][k][h] = acc[k]; }
    }
    __syncthreads();
    if (jg == 0){
        #pragma unroll
        for (int k = 0; k < TI; k++){
            float st = s[k] + ps[0][k][h] + ps[1][k][h] + ps[2][k][h];
            float at = acc[k] + pa[0][k][h] + pa[1][k][h] + pa[2][k][h];
            float res = fmaf(at, __builtin_amdgcn_rcpf(st + 1e-16f), hbuf[(size_t)ib[k]*HD + h]);
            if (i0 + k < NPER){
                hbuf[(size_t)ib[k]*HD + h] = res;
                if (outp) outp[(size_t)ib[k]*HD + h] = res;
            }
        }
    }
}

extern "C" void kernel_launch(void* const* d_in, const int* in_sizes, int n_in,
                              void* d_out, int out_size, void* d_ws, size_t ws_size,
                              hipStream_t stream) {
    const float* x      = (const float*)d_in[0];
    const float* demand = (const float*)d_in[1];
    const float* eai    = (const float*)d_in[2];
    // d_in[3] edge_index: known constant structure, unused
    const float* fnw = (const float*)d_in[4];
    const float* fnb = (const float*)d_in[5];
    const float* bng = (const float*)d_in[6];
    const float* bnb = (const float*)d_in[7];
    const float* few = (const float*)d_in[8];
    // d_in[9] fc_edge_b cancels in BatchNorm
    const float* beg = (const float*)d_in[10];
    const float* beb = (const float*)d_in[11];
    const float* fcw = (const float*)d_in[12];
    const float* fcb = (const float*)d_in[13];
    const float* aw  = (const float*)d_in[14];
    const float* ab  = (const float*)d_in[15];
    float* out = (float*)d_out;

    float* w     = (float*)d_ws;
    float* hbuf  = w;
    float* tbuf  = w + (size_t)NN*HD;
    float* Ubuf  = w + (size_t)2*NN*HD;
    float* Vbuf  = w + (size_t)3*NN*HD;
    float* stats = w + (size_t)4*NN*HD;   // 4 floats
    float* c1    = stats + 4;             // 3*128
    float* dv    = c1 + 3*HD;             // 3*128
    float* CW    = dv + 3*HD;             // 3*2*128*128

    hipLaunchKernelGGL(k_zero, dim3(1), dim3(64), 0, stream, stats, 4);
    hipLaunchKernelGGL(k_reduce_eai, dim3(256), dim3(256), 0, stream, eai, stats);
    hipLaunchKernelGGL(k_setup, dim3(1), dim3(HD), 0, stream, stats, few, beg, beb, aw, ab, c1, dv);
    hipLaunchKernelGGL(k_comp, dim3(3*129), dim3(HD), 0, stream, fcw, fcb, aw, CW, dv);
    hipLaunchKernelGGL(k_node_bn, dim3(HD), dim3(256), 0, stream, x, demand, fnw, fnb, bng, bnb, hbuf);
    for (int l = 0; l < 3; l++){
        hipLaunchKernelGGL(k_tuv3, dim3(NN/8), dim3(256), 0, stream,
                           hbuf, fcw, fcb, CW, tbuf, Ubuf, Vbuf, l);
        hipLaunchKernelGGL(k_attn4, dim3(64*NBLK), dim3(512), 0, stream,
                           Ubuf, Vbuf, tbuf, eai, c1, dv, hbuf, l, (l == 2) ? out : (float*)nullptr);
    }
}

// Round 5
// 192.330 us; speedup vs baseline: 1.2634x; 1.0030x over previous
//
#include <hip/hip_runtime.h>
#include <math.h>

#define NN   6464      // total nodes
#define NPER 101
#define HD   128
#define HE   16
#define NE   652864    // 64*101*101
#define PERB 10201     // 101*101
#define EPSB 1e-5f
#define SLOPE 0.2f
#define TI   4         // dest nodes per attention block
#define NBLK 26        // ceil(101/4)
#define JW   13        // j-rows per wave (8 waves cover 101)
#define L2E  1.44269504088896340736f

__global__ void k_zero(float* p, int n){
    int i = blockIdx.x*blockDim.x + threadIdx.x;
    if (i < n) p[i] = 0.f;
}

__global__ void k_reduce_eai(const float* __restrict__ eai, float* __restrict__ stats){
    __shared__ float ls[256], ls2[256];
    float s = 0.f, s2 = 0.f;
    for (int i = blockIdx.x*256 + threadIdx.x; i < NE; i += gridDim.x*256){
        float v = eai[i]; s += v; s2 += v*v;
    }
    int tid = threadIdx.x;
    ls[tid] = s; ls2[tid] = s2; __syncthreads();
    for (int o = 128; o > 0; o >>= 1){
        if (tid < o){ ls[tid] += ls[tid+o]; ls2[tid] += ls2[tid+o]; }
        __syncthreads();
    }
    if (tid == 0){ atomicAdd(&stats[0], ls[0]); atomicAdd(&stats[1], ls2[0]); }
}

// c1[h], dv[h] per layer from edge-attr batch stats (both pre-scaled by L2E).
__global__ void k_setup(const float* __restrict__ stats, const float* __restrict__ few,
                        const float* __restrict__ beg, const float* __restrict__ beb,
                        const float* __restrict__ attn_w, const float* __restrict__ attn_b,
                        float* __restrict__ c1, float* __restrict__ dv){
    __shared__ float sA[HE], sB[HE];
    int tid = threadIdx.x;                 // 128 threads = h
    float mean = stats[0] * (1.f/NE);
    float var  = stats[1] * (1.f/NE) - mean*mean;
    if (tid < HE){
        float w = few[tid];
        float a = w * rsqrtf(var*w*w + EPSB) * beg[tid];
        sA[tid] = a; sB[tid] = beb[tid] - mean*a;
    }
    __syncthreads();
    for (int l = 0; l < 3; l++){
        const float* W = attn_w + (l*272 + 256)*HD;   // We rows (256..271)
        float a1 = 0.f, a2 = 0.f;
        for (int k = 0; k < HE; k++){
            float wv = W[k*HD + tid];
            a1 += sA[k]*wv; a2 += sB[k]*wv;
        }
        c1[l*HD + tid] = a1 * L2E;
        dv[l*HD + tid] = (a2 + attn_b[l*HD + tid]) * L2E;
    }
}

// Composite matrices: CWi = (fc_w[l] @ Wi)*L2E, CWj = (fc_w[l] @ Wj)*L2E.
// Row r==128 handles the bias row: dv += (fc_b@Wi + fc_b@Wj)*L2E (runs after k_setup).
__global__ __launch_bounds__(128) void k_comp(const float* __restrict__ fc_w, const float* __restrict__ fc_b,
                     const float* __restrict__ attn_w, float* __restrict__ CW, float* __restrict__ dv){
    int blk = blockIdx.x;
    int l = blk / 129, r = blk - l*129;
    int hh = threadIdx.x;
    const float* Wi = attn_w + (size_t)l*272*HD;
    const float* Wj = Wi + HD*HD;
    const float* Fr = (r < HD) ? (fc_w + (size_t)l*HD*HD + (size_t)r*HD) : (fc_b + l*HD);
    float ai = 0.f, aj = 0.f;
    for (int m = 0; m < HD; m++){
        float f = Fr[m];
        ai = fmaf(f, Wi[m*HD + hh], ai);
        aj = fmaf(f, Wj[m*HD + hh], aj);
    }
    if (r < HD){
        CW[((size_t)l*2    )*HD*HD + (size_t)r*HD + hh] = ai * L2E;
        CW[((size_t)l*2 + 1)*HD*HD + (size_t)r*HD + hh] = aj * L2E;
    } else {
        dv[l*HD + hh] += (ai + aj) * L2E;
    }
}

// h0 = [x,demand] @ fc_node_w + b, training-mode BatchNorm over all N rows.
__global__ __launch_bounds__(256) void k_node_bn(const float* __restrict__ x, const float* __restrict__ demand,
                          const float* __restrict__ w, const float* __restrict__ b,
                          const float* __restrict__ g, const float* __restrict__ beta,
                          float* __restrict__ hbuf){
    int k = blockIdx.x, tid = threadIdx.x;
    float w0 = w[k], w1 = w[HD+k], w2 = w[2*HD+k], bb = b[k];
    float s = 0.f, s2 = 0.f;
    for (int n = tid; n < NN; n += 256){
        float p = x[2*n]*w0 + x[2*n+1]*w1 + demand[n]*w2 + bb;
        s += p; s2 += p*p;
    }
    __shared__ float ls[256], ls2[256];
    ls[tid] = s; ls2[tid] = s2; __syncthreads();
    for (int o = 128; o > 0; o >>= 1){
        if (tid < o){ ls[tid] += ls[tid+o]; ls2[tid] += ls2[tid+o]; }
        __syncthreads();
    }
    __shared__ float smu, srs;
    if (tid == 0){
        float mu = ls[0]*(1.f/NN);
        float var = ls2[0]*(1.f/NN) - mu*mu;
        smu = mu; srs = rsqrtf(var + EPSB);
    }
    __syncthreads();
    float mu = smu, rs = srs, gg = g[k], be = beta[k];
    for (int n = tid; n < NN; n += 256){
        float p = x[2*n]*w0 + x[2*n+1]*w1 + demand[n]*w2 + bb;
        hbuf[n*HD + k] = (p - mu)*rs*gg + be;
    }
}

// One pass: t = h@F + fc_b;  U = h@CWi (L2E-scaled, bias folded into dv);  V = h@CWj.
__global__ __launch_bounds__(256) void k_tuv3(const float* __restrict__ hbuf,
                     const float* __restrict__ fc_w, const float* __restrict__ fc_b,
                     const float* __restrict__ CW,
                     float* __restrict__ t, float* __restrict__ U, float* __restrict__ V, int l){
    __shared__ float hs[HD][12];           // [k][node], pad to 12
    int n0 = blockIdx.x * 8;
    int tid = threadIdx.x;
    for (int idx = tid; idx < 8*HD; idx += 256){
        int n = idx >> 7, k = idx & (HD-1);
        hs[k][n] = hbuf[(size_t)(n0+n)*HD + k];
    }
    __syncthreads();
    int hh = tid & (HD-1), ng = tid >> 7;  // nodes 4ng..4ng+3
    const float* Ft = fc_w + (size_t)l*HD*HD + hh;
    const float* Wi = CW + (size_t)l*2*HD*HD + hh;
    const float* Wj = Wi + HD*HD;
    float bias = fc_b[l*HD + hh];
    float t0=bias,t1=bias,t2=bias,t3=bias;
    float u0=0,u1=0,u2=0,u3=0, v0=0,v1=0,v2=0,v3=0;
    #pragma unroll 4
    for (int k = 0; k < HD; k++){
        float wt = Ft[(size_t)k*HD];
        float wi = Wi[(size_t)k*HD];
        float wj = Wj[(size_t)k*HD];
        float4 hv = *(const float4*)&hs[k][ng*4];
        t0 = fmaf(hv.x, wt, t0); t1 = fmaf(hv.y, wt, t1);
        t2 = fmaf(hv.z, wt, t2); t3 = fmaf(hv.w, wt, t3);
        u0 = fmaf(hv.x, wi, u0); u1 = fmaf(hv.y, wi, u1);
        u2 = fmaf(hv.z, wi, u2); u3 = fmaf(hv.w, wi, u3);
        v0 = fmaf(hv.x, wj, v0); v1 = fmaf(hv.y, wj, v1);
        v2 = fmaf(hv.z, wj, v2); v3 = fmaf(hv.w, wj, v3);
    }
    size_t nb = (size_t)(n0 + ng*4)*HD + hh;
    t[nb       ] = t0; t[nb +   HD] = t1; t[nb + 2*HD] = t2; t[nb + 3*HD] = t3;
    U[nb       ] = u0; U[nb +   HD] = u1; U[nb + 2*HD] = u2; U[nb + 3*HD] = u3;
    V[nb       ] = v0; V[nb +   HD] = v1; V[nb + 2*HD] = v2; V[nb + 3*HD] = v3;
}

// Attention v5: 512 threads = 8 waves; wave jg owns j-rows [13jg, min(13jg+13,101)).
// Lane = h-pair (float2 V/t loads); 4-row register-pipelined chunks; partials via LDS.
__global__ __launch_bounds__(512) void k_attn5(const float* __restrict__ U, const float* __restrict__ V,
                      const float* __restrict__ t, const float* __restrict__ eai,
                      const float* __restrict__ c1, const float* __restrict__ dv,
                      float* __restrict__ hbuf, int l, float* __restrict__ outp){
    __shared__ float4 es4[NPER];
    __shared__ float ps[8][TI][HD], pa[8][TI][HD];
    int blk = blockIdx.x;
    int b = blk / NBLK, c = blk - b*NBLK;
    int i0 = c*TI;
    int tid = threadIdx.x;
    int q  = tid & 63;
    int jg = tid >> 6;                     // wave id 0..7
    int h0 = 2*q;                          // channel pair h0, h0+1

    for (int idx = tid; idx < NPER*TI; idx += 512){
        int j = idx >> 2, k = idx & 3;
        int i = i0 + k; if (i > NPER-1) i = NPER-1;
        ((float*)&es4[j])[k] = eai[(size_t)b*PERB + (size_t)j*NPER + i];
    }
    float2 c1h = *(const float2*)&c1[l*HD + h0];
    float2 dd  = *(const float2*)&dv[l*HD + h0];
    float2 base[TI], s[TI], acc[TI];
    #pragma unroll
    for (int k = 0; k < TI; k++){
        int i = i0 + k; if (i > NPER-1) i = NPER-1;
        float2 uu = *(const float2*)&U[(size_t)(b*NPER + i)*HD + h0];
        base[k].x = uu.x + dd.x; base[k].y = uu.y + dd.y;
        s[k].x = 0.f; s[k].y = 0.f; acc[k].x = 0.f; acc[k].y = 0.f;
    }
    __syncthreads();

    const float2* Vb = (const float2*)(V + (size_t)(b*NPER)*HD) + q;   // row stride 64
    const float2* tb = (const float2*)(t + (size_t)(b*NPER)*HD) + q;
    int j0 = jg*JW;
    int j1 = j0 + JW; if (j1 > NPER) j1 = NPER;   // 13 or 10 rows (wave-uniform)
    float2 Va[4], Ta[4], Vn[4], Tn[4];
    #pragma unroll
    for (int r = 0; r < 4; r++){
        int jr = j0 + r; if (jr > j1-1) jr = j1-1;
        Va[r] = Vb[(size_t)jr*64];
        Ta[r] = tb[(size_t)jr*64];
    }
    #pragma unroll
    for (int cch = 0; cch < 4; cch++){
        int jb = j0 + cch*4;
        #pragma unroll
        for (int r = 0; r < 4; r++){       // prefetch next chunk (clamped, always safe)
            int jr = jb + 4 + r; if (jr > j1-1) jr = j1-1;
            Vn[r] = Vb[(size_t)jr*64];
            Tn[r] = tb[(size_t)jr*64];
        }
        #pragma unroll
        for (int r = 0; r < 4; r++){
            int j = jb + r;
            if (j < j1){                   // wave-uniform branch
                float4 e4 = es4[j];
                float ev[TI] = {e4.x, e4.y, e4.z, e4.w};
                float2 vj = Va[r], tj = Ta[r];
                #pragma unroll
                for (int k = 0; k < TI; k++){
                    float zx = fmaf(ev[k], c1h.x, base[k].x + vj.x);
                    float zy = fmaf(ev[k], c1h.y, base[k].y + vj.y);
                    zx = fmaxf(zx, SLOPE*zx);
                    zy = fmaxf(zy, SLOPE*zy);
                    float wx = __builtin_amdgcn_exp2f(zx);
                    float wy = __builtin_amdgcn_exp2f(zy);
                    s[k].x += wx;           s[k].y += wy;
                    acc[k].x = fmaf(wx, tj.x, acc[k].x);
                    acc[k].y = fmaf(wy, tj.y, acc[k].y);
                }
            }
        }
        #pragma unroll
        for (int r = 0; r < 4; r++){ Va[r] = Vn[r]; Ta[r] = Tn[r]; }
    }
    #pragma unroll
    for (int k = 0; k < TI; k++){
        *(float2*)&ps[jg][k][h0] = s[k];
        *(float2*)&pa[jg][k][h0] = acc[k];
    }
    __syncthreads();
    {   // combine: thread = (k = tid>>7, h = tid&127)
        int k = tid >> 7, h = tid & (HD-1);
        int i = i0 + k;
        if (i < NPER){
            float st = 0.f, at = 0.f;
            #pragma unroll
            for (int g = 0; g < 8; g++){ st += ps[g][k][h]; at += pa[g][k][h]; }
            size_t o = (size_t)(b*NPER + i)*HD + h;
            float res = fmaf(at, __builtin_amdgcn_rcpf(st + 1e-16f), hbuf[o]);
            hbuf[o] = res;
            if (outp) outp[o] = res;
        }
    }
}

extern "C" void kernel_launch(void* const* d_in, const int* in_sizes, int n_in,
                              void* d_out, int out_size, void* d_ws, size_t ws_size,
                              hipStream_t stream) {
    const float* x      = (const float*)d_in[0];
    const float* demand = (const float*)d_in[1];
    const float* eai    = (const float*)d_in[2];
    // d_in[3] edge_index: known constant structure, unused
    const float* fnw = (const float*)d_in[4];
    const float* fnb = (const float*)d_in[5];
    const float* bng = (const float*)d_in[6];
    const float* bnb = (const float*)d_in[7];
    const float* few = (const float*)d_in[8];
    // d_in[9] fc_edge_b cancels in BatchNorm
    const float* beg = (const float*)d_in[10];
    const float* beb = (const float*)d_in[11];
    const float* fcw = (const float*)d_in[12];
    const float* fcb = (const float*)d_in[13];
    const float* aw  = (const float*)d_in[14];
    const float* ab  = (const float*)d_in[15];
    float* out = (float*)d_out;

    float* w     = (float*)d_ws;
    float* hbuf  = w;
    float* tbuf  = w + (size_t)NN*HD;
    float* Ubuf  = w + (size_t)2*NN*HD;
    float* Vbuf  = w + (size_t)3*NN*HD;
    float* stats = w + (size_t)4*NN*HD;   // 4 floats
    float* c1    = stats + 4;             // 3*128
    float* dv    = c1 + 3*HD;             // 3*128
    float* CW    = dv + 3*HD;             // 3*2*128*128

    hipLaunchKernelGGL(k_zero, dim3(1), dim3(64), 0, stream, stats, 4);
    hipLaunchKernelGGL(k_reduce_eai, dim3(256), dim3(256), 0, stream, eai, stats);
    hipLaunchKernelGGL(k_setup, dim3(1), dim3(HD), 0, stream, stats, few, beg, beb, aw, ab, c1, dv);
    hipLaunchKernelGGL(k_comp, dim3(3*129), dim3(HD), 0, stream, fcw, fcb, aw, CW, dv);
    hipLaunchKernelGGL(k_node_bn, dim3(HD), dim3(256), 0, stream, x, demand, fnw, fnb, bng, bnb, hbuf);
    for (int l = 0; l < 3; l++){
        hipLaunchKernelGGL(k_tuv3, dim3(NN/8), dim3(256), 0, stream,
                           hbuf, fcw, fcb, CW, tbuf, Ubuf, Vbuf, l);
        hipLaunchKernelGGL(k_attn5, dim3(64*NBLK), dim3(512), 0, stream,
                           Ubuf, Vbuf, tbuf, eai, c1, dv, hbuf, l, (l == 2) ? out : (float*)nullptr);
    }
}

// Round 6
// 178.481 us; speedup vs baseline: 1.3614x; 1.0776x over previous
//
#include <hip/hip_runtime.h>
#include <math.h>

#define NN   6464      // total nodes
#define NPER 101
#define HD   128
#define HE   16
#define NE   652864    // 64*101*101
#define PERB 10201     // 101*101
#define EPSB 1e-5f
#define SLOPE 0.2f
#define TI   4         // dest nodes per attention block
#define NBLK 26        // ceil(101/4)
#define JW   13        // j-rows per wave (8 waves cover 101)
#define L2E  1.44269504088896340736f
#define NO   384       // t|U|V concatenated output width

__global__ void k_zero(float* p, int n){
    int i = blockIdx.x*blockDim.x + threadIdx.x;
    if (i < n) p[i] = 0.f;
}

__global__ void k_reduce_eai(const float* __restrict__ eai, float* __restrict__ stats){
    __shared__ float ls[256], ls2[256];
    float s = 0.f, s2 = 0.f;
    for (int i = blockIdx.x*256 + threadIdx.x; i < NE; i += gridDim.x*256){
        float v = eai[i]; s += v; s2 += v*v;
    }
    int tid = threadIdx.x;
    ls[tid] = s; ls2[tid] = s2; __syncthreads();
    for (int o = 128; o > 0; o >>= 1){
        if (tid < o){ ls[tid] += ls[tid+o]; ls2[tid] += ls2[tid+o]; }
        __syncthreads();
    }
    if (tid == 0){ atomicAdd(&stats[0], ls[0]); atomicAdd(&stats[1], ls2[0]); }
}

// c1[h], dv[h] per layer from edge-attr batch stats (both pre-scaled by L2E).
__global__ void k_setup(const float* __restrict__ stats, const float* __restrict__ few,
                        const float* __restrict__ beg, const float* __restrict__ beb,
                        const float* __restrict__ attn_w, const float* __restrict__ attn_b,
                        float* __restrict__ c1, float* __restrict__ dv){
    __shared__ float sA[HE], sB[HE];
    int tid = threadIdx.x;                 // 128 threads = h
    float mean = stats[0] * (1.f/NE);
    float var  = stats[1] * (1.f/NE) - mean*mean;
    if (tid < HE){
        float w = few[tid];
        float a = w * rsqrtf(var*w*w + EPSB) * beg[tid];
        sA[tid] = a; sB[tid] = beb[tid] - mean*a;
    }
    __syncthreads();
    for (int l = 0; l < 3; l++){
        const float* W = attn_w + (l*272 + 256)*HD;   // We rows (256..271)
        float a1 = 0.f, a2 = 0.f;
        for (int k = 0; k < HE; k++){
            float wv = W[k*HD + tid];
            a1 += sA[k]*wv; a2 += sB[k]*wv;
        }
        c1[l*HD + tid] = a1 * L2E;
        dv[l*HD + tid] = (a2 + attn_b[l*HD + tid]) * L2E;
    }
}

// Build Wcat[l][k][384] = [ F | (F@Wi)*L2E | (F@Wj)*L2E ] rows; bias row r==128
// adds (fc_b@Wi + fc_b@Wj)*L2E into dv (t-bias handled in k_gemm's acc init).
__global__ __launch_bounds__(128) void k_comp(const float* __restrict__ fc_w, const float* __restrict__ fc_b,
                     const float* __restrict__ attn_w, float* __restrict__ Wcat, float* __restrict__ dv){
    int blk = blockIdx.x;
    int l = blk / 129, r = blk - l*129;
    int hh = threadIdx.x;
    const float* Wi = attn_w + (size_t)l*272*HD;
    const float* Wj = Wi + HD*HD;
    const float* Fr = (r < HD) ? (fc_w + (size_t)l*HD*HD + (size_t)r*HD) : (fc_b + l*HD);
    float ai = 0.f, aj = 0.f;
    for (int m = 0; m < HD; m++){
        float f = Fr[m];
        ai = fmaf(f, Wi[m*HD + hh], ai);
        aj = fmaf(f, Wj[m*HD + hh], aj);
    }
    if (r < HD){
        float* row = Wcat + ((size_t)l*HD + r)*NO;
        row[hh]        = Fr[hh];          // F copy (t-part)
        row[HD  + hh]  = ai * L2E;        // CWi
        row[2*HD + hh] = aj * L2E;        // CWj
    } else {
        dv[l*HD + hh] += (ai + aj) * L2E;
    }
}

// h0 = [x,demand] @ fc_node_w + b, training-mode BatchNorm over all N rows.
__global__ __launch_bounds__(256) void k_node_bn(const float* __restrict__ x, const float* __restrict__ demand,
                          const float* __restrict__ w, const float* __restrict__ b,
                          const float* __restrict__ g, const float* __restrict__ beta,
                          float* __restrict__ hbuf){
    int k = blockIdx.x, tid = threadIdx.x;
    float w0 = w[k], w1 = w[HD+k], w2 = w[2*HD+k], bb = b[k];
    float s = 0.f, s2 = 0.f;
    for (int n = tid; n < NN; n += 256){
        float p = x[2*n]*w0 + x[2*n+1]*w1 + demand[n]*w2 + bb;
        s += p; s2 += p*p;
    }
    __shared__ float ls[256], ls2[256];
    ls[tid] = s; ls2[tid] = s2; __syncthreads();
    for (int o = 128; o > 0; o >>= 1){
        if (tid < o){ ls[tid] += ls[tid+o]; ls2[tid] += ls2[tid+o]; }
        __syncthreads();
    }
    __shared__ float smu, srs;
    if (tid == 0){
        float mu = ls[0]*(1.f/NN);
        float var = ls2[0]*(1.f/NN) - mu*mu;
        smu = mu; srs = rsqrtf(var + EPSB);
    }
    __syncthreads();
    float mu = smu, rs = srs, gg = g[k], be = beta[k];
    for (int n = tid; n < NN; n += 256){
        float p = x[2*n]*w0 + x[2*n+1]*w1 + demand[n]*w2 + bb;
        hbuf[n*HD + k] = (p - mu)*rs*gg + be;
    }
}

// Tiled GEMM: TUV[6464][384] = hbuf[6464][128] @ Wcat_l[128][384] (+ fc_b on t-tile).
// 64x128 block tile, thread = 4m x (4+4)n, BK=16, reg-double-buffered staging.
#define BM 64
#define BN 128
#define BK 16
__global__ __launch_bounds__(256) void k_gemm(const float* __restrict__ hbuf,
                     const float* __restrict__ Wcat, const float* __restrict__ fc_b,
                     float* __restrict__ TUV, int l){
    __shared__ float As[BK][68];       // [k][m], pad 68 (16B-aligned rows, spread banks)
    __shared__ float Bs[BK][BN];       // [k][n]
    int bi = blockIdx.x;
    int bm = bi / 3, bn = bi - bm*3;
    int m0 = bm*BM, o0 = bn*BN;
    int tid = threadIdx.x;
    int tx = tid & 15, ty = tid >> 4;  // n-group, m-group
    const float* Wl = Wcat + (size_t)l*HD*NO;

    // acc init: bias only on the t-tile (bn==0); U/V biases folded into dv.
    float acc[4][8];
    #pragma unroll
    for (int i = 0; i < 4; i++)
        #pragma unroll
        for (int j = 0; j < 8; j++) acc[i][j] = 0.f;
    if (bn == 0){
        const float* fb = fc_b + l*HD;
        #pragma unroll
        for (int j = 0; j < 4; j++){
            float b0 = fb[4*tx + j], b1 = fb[64 + 4*tx + j];
            #pragma unroll
            for (int i = 0; i < 4; i++){ acc[i][j] = b0; acc[i][j+4] = b1; }
        }
    }

    // staging indices
    int ar = tid >> 2, ac4 = tid & 3;            // A: row m0+ar, k-quad ac4
    int bq0 = tid, bq1 = tid + 256;              // B: two float4s
    int bc0 = bq0 >> 5, bn40 = bq0 & 31;
    int bc1 = bq1 >> 5, bn41 = bq1 & 31;

    float4 ra  = *(const float4*)&hbuf[(size_t)(m0 + ar)*HD + 0 + 4*ac4];
    float4 rb0 = *(const float4*)&Wl[(size_t)(0 + bc0)*NO + o0 + 4*bn40];
    float4 rb1 = *(const float4*)&Wl[(size_t)(0 + bc1)*NO + o0 + 4*bn41];

    for (int ch = 0; ch < 8; ch++){
        __syncthreads();
        As[4*ac4+0][ar] = ra.x; As[4*ac4+1][ar] = ra.y;
        As[4*ac4+2][ar] = ra.z; As[4*ac4+3][ar] = ra.w;
        *(float4*)&Bs[bc0][4*bn40] = rb0;
        *(float4*)&Bs[bc1][4*bn41] = rb1;
        __syncthreads();
        if (ch < 7){
            int k0 = (ch+1)*BK;
            ra  = *(const float4*)&hbuf[(size_t)(m0 + ar)*HD + k0 + 4*ac4];
            rb0 = *(const float4*)&Wl[(size_t)(k0 + bc0)*NO + o0 + 4*bn40];
            rb1 = *(const float4*)&Wl[(size_t)(k0 + bc1)*NO + o0 + 4*bn41];
        }
        #pragma unroll
        for (int c = 0; c < BK; c++){
            float4 av  = *(const float4*)&As[c][4*ty];
            float4 bv0 = *(const float4*)&Bs[c][4*tx];
            float4 bv1 = *(const float4*)&Bs[c][64 + 4*tx];
            float a[4] = {av.x, av.y, av.z, av.w};
            float b[8] = {bv0.x, bv0.y, bv0.z, bv0.w, bv1.x, bv1.y, bv1.z, bv1.w};
            #pragma unroll
            for (int i = 0; i < 4; i++)
                #pragma unroll
                for (int j = 0; j < 8; j++)
                    acc[i][j] = fmaf(a[i], b[j], acc[i][j]);
        }
    }
    #pragma unroll
    for (int i = 0; i < 4; i++){
        size_t row = (size_t)(m0 + 4*ty + i)*NO + o0;
        *(float4*)&TUV[row + 4*tx]      = make_float4(acc[i][0], acc[i][1], acc[i][2], acc[i][3]);
        *(float4*)&TUV[row + 64 + 4*tx] = make_float4(acc[i][4], acc[i][5], acc[i][6], acc[i][7]);
    }
}

// Attention v6: identical to v5 except (1) TUV strided layout, (2) XCD-aware
// block swizzle so all blocks of a batch (8 batches/XCD) share one XCD's L2.
__global__ __launch_bounds__(512) void k_attn6(const float* __restrict__ TUV,
                      const float* __restrict__ eai,
                      const float* __restrict__ c1, const float* __restrict__ dv,
                      float* __restrict__ hbuf, int l, float* __restrict__ outp){
    __shared__ float4 es4[NPER];
    __shared__ float ps[8][TI][HD], pa[8][TI][HD];
    int blk = blockIdx.x;
    // swizzle: xcd = blk&7 (HW round-robin); batches b with b%8==xcd stay on xcd
    int xcd = blk & 7, r = blk >> 3;
    int b = xcd + 8*(r & 7), c = r >> 3;   // c in [0,26)
    int i0 = c*TI;
    int tid = threadIdx.x;
    int q  = tid & 63;
    int jg = tid >> 6;                     // wave id 0..7
    int h0 = 2*q;                          // channel pair h0, h0+1

    for (int idx = tid; idx < NPER*TI; idx += 512){
        int j = idx >> 2, k = idx & 3;
        int i = i0 + k; if (i > NPER-1) i = NPER-1;
        ((float*)&es4[j])[k] = eai[(size_t)b*PERB + (size_t)j*NPER + i];
    }
    float2 c1h = *(const float2*)&c1[l*HD + h0];
    float2 dd  = *(const float2*)&dv[l*HD + h0];
    float2 base[TI], s[TI], acc[TI];
    #pragma unroll
    for (int k = 0; k < TI; k++){
        int i = i0 + k; if (i > NPER-1) i = NPER-1;
        float2 uu = *(const float2*)&TUV[(size_t)(b*NPER + i)*NO + HD + h0];
        base[k].x = uu.x + dd.x; base[k].y = uu.y + dd.y;
        s[k].x = 0.f; s[k].y = 0.f; acc[k].x = 0.f; acc[k].y = 0.f;
    }
    __syncthreads();

    const float2* Vb = (const float2*)(TUV + (size_t)(b*NPER)*NO + 2*HD) + q;  // row stride 192
    const float2* tb = (const float2*)(TUV + (size_t)(b*NPER)*NO) + q;
    int j0 = jg*JW;
    int j1 = j0 + JW; if (j1 > NPER) j1 = NPER;   // 13 or 10 rows (wave-uniform)
    float2 Va[4], Ta[4], Vn[4], Tn[4];
    #pragma unroll
    for (int rr = 0; rr < 4; rr++){
        int jr = j0 + rr; if (jr > j1-1) jr = j1-1;
        Va[rr] = Vb[(size_t)jr*192];
        Ta[rr] = tb[(size_t)jr*192];
    }
    #pragma unroll
    for (int cch = 0; cch < 4; cch++){
        int jb = j0 + cch*4;
        #pragma unroll
        for (int rr = 0; rr < 4; rr++){    // prefetch next chunk (clamped, safe)
            int jr = jb + 4 + rr; if (jr > j1-1) jr = j1-1;
            Vn[rr] = Vb[(size_t)jr*192];
            Tn[rr] = tb[(size_t)jr*192];
        }
        #pragma unroll
        for (int rr = 0; rr < 4; rr++){
            int j = jb + rr;
            if (j < j1){                   // wave-uniform branch
                float4 e4 = es4[j];
                float ev[TI] = {e4.x, e4.y, e4.z, e4.w};
                float2 vj = Va[rr], tj = Ta[rr];
                #pragma unroll
                for (int k = 0; k < TI; k++){
                    float zx = fmaf(ev[k], c1h.x, base[k].x + vj.x);
                    float zy = fmaf(ev[k], c1h.y, base[k].y + vj.y);
                    zx = fmaxf(zx, SLOPE*zx);
                    zy = fmaxf(zy, SLOPE*zy);
                    float wx = __builtin_amdgcn_exp2f(zx);
                    float wy = __builtin_amdgcn_exp2f(zy);
                    s[k].x += wx;           s[k].y += wy;
                    acc[k].x = fmaf(wx, tj.x, acc[k].x);
                    acc[k].y = fmaf(wy, tj.y, acc[k].y);
                }
            }
        }
        #pragma unroll
        for (int rr = 0; rr < 4; rr++){ Va[rr] = Vn[rr]; Ta[rr] = Tn[rr]; }
    }
    #pragma unroll
    for (int k = 0; k < TI; k++){
        *(float2*)&ps[jg][k][h0] = s[k];
        *(float2*)&pa[jg][k][h0] = acc[k];
    }
    __syncthreads();
    {   // combine: thread = (k = tid>>7, h = tid&127)
        int k = tid >> 7, h = tid & (HD-1);
        int i = i0 + k;
        if (i < NPER){
            float st = 0.f, at = 0.f;
            #pragma unroll
            for (int g = 0; g < 8; g++){ st += ps[g][k][h]; at += pa[g][k][h]; }
            size_t o = (size_t)(b*NPER + i)*HD + h;
            float res = fmaf(at, __builtin_amdgcn_rcpf(st + 1e-16f), hbuf[o]);
            hbuf[o] = res;
            if (outp) outp[o] = res;
        }
    }
}

extern "C" void kernel_launch(void* const* d_in, const int* in_sizes, int n_in,
                              void* d_out, int out_size, void* d_ws, size_t ws_size,
                              hipStream_t stream) {
    const float* x      = (const float*)d_in[0];
    const float* demand = (const float*)d_in[1];
    const float* eai    = (const float*)d_in[2];
    // d_in[3] edge_index: known constant structure, unused
    const float* fnw = (const float*)d_in[4];
    const float* fnb = (const float*)d_in[5];
    const float* bng = (const float*)d_in[6];
    const float* bnb = (const float*)d_in[7];
    const float* few = (const float*)d_in[8];
    // d_in[9] fc_edge_b cancels in BatchNorm
    const float* beg = (const float*)d_in[10];
    const float* beb = (const float*)d_in[11];
    const float* fcw = (const float*)d_in[12];
    const float* fcb = (const float*)d_in[13];
    const float* aw  = (const float*)d_in[14];
    const float* ab  = (const float*)d_in[15];
    float* out = (float*)d_out;

    float* w     = (float*)d_ws;
    float* hbuf  = w;                         // NN*128
    float* TUV   = w + (size_t)NN*HD;         // NN*384
    float* stats = TUV + (size_t)NN*NO;       // 4
    float* c1    = stats + 4;                 // 3*128
    float* dv    = c1 + 3*HD;                 // 3*128
    float* Wcat  = dv + 3*HD;                 // 3*128*384

    hipLaunchKernelGGL(k_zero, dim3(1), dim3(64), 0, stream, stats, 4);
    hipLaunchKernelGGL(k_reduce_eai, dim3(256), dim3(256), 0, stream, eai, stats);
    hipLaunchKernelGGL(k_setup, dim3(1), dim3(HD), 0, stream, stats, few, beg, beb, aw, ab, c1, dv);
    hipLaunchKernelGGL(k_comp, dim3(3*129), dim3(HD), 0, stream, fcw, fcb, aw, Wcat, dv);
    hipLaunchKernelGGL(k_node_bn, dim3(HD), dim3(256), 0, stream, x, demand, fnw, fnb, bng, bnb, hbuf);
    for (int l = 0; l < 3; l++){
        hipLaunchKernelGGL(k_gemm, dim3(101*3), dim3(256), 0, stream,
                           hbuf, Wcat, fcb, TUV, l);
        hipLaunchKernelGGL(k_attn6, dim3(64*NBLK), dim3(512), 0, stream,
                           TUV, eai, c1, dv, hbuf, l, (l == 2) ? out : (float*)nullptr);
    }
}